// Round 1
// baseline (238.397 us; speedup 1.0000x reference)
//
#include <hip/hip_runtime.h>

// Problem: B=8, C=128, H=W=64 -> N=4096 tokens/batch, 32768 total. d_qk=32.
// LN(channel) -> Q/K/V 1x1 conv -> full spatial attention -> Wo + bias + residual.

#define NB 8
#define CCH 128
#define NTOK 4096      // tokens per batch (H*W)
#define DQK 32
#define KT 64          // key tile

typedef __attribute__((ext_vector_type(8))) short bf16x8;  // 8 bf16 = 4 VGPR
typedef __attribute__((ext_vector_type(4))) float f32x4;
typedef unsigned short u16;
typedef unsigned int u32;

static __device__ __forceinline__ f32x4 mfma16(bf16x8 a, bf16x8 b, f32x4 c) {
  return __builtin_amdgcn_mfma_f32_16x16x32_bf16(a, b, c, 0, 0, 0);
}

static __device__ __forceinline__ u16 f2bf(float f) {
  union { float f; u32 u; } cv; cv.f = f;
  u32 u = cv.u;
  u += 0x7fffu + ((u >> 16) & 1u);   // round-to-nearest-even
  return (u16)(u >> 16);
}

// ---------------- kernel 0: convert weights to bf16, combined [320][128] ----
// rows 0..31 Wq, 32..63 Wk, 64..191 Wv, 192..319 Wo
__global__ __launch_bounds__(256) void wconv_kernel(
    const float* __restrict__ Wq, const float* __restrict__ Wk,
    const float* __restrict__ Wv, const float* __restrict__ Wo,
    u16* __restrict__ wcomb) {
  int idx = blockIdx.x * 256 + threadIdx.x;   // 0..40959
  int r = idx >> 7;
  float v;
  if (r < 32)        v = Wq[idx];
  else if (r < 64)   v = Wk[idx - 4096];
  else if (r < 192)  v = Wv[idx - 8192];
  else               v = Wo[idx - 24576];
  wcomb[idx] = f2bf(v);
}

// ---------------- kernel 1: LayerNorm over C, write token-major bf16 --------
__global__ __launch_bounds__(256) void ln_kernel(
    const float* __restrict__ x, const float* __restrict__ gamma,
    const float* __restrict__ beta, u16* __restrict__ xn) {
  __shared__ float tile[128][64];    // [c][pos] 32 KB
  __shared__ float red[2][4][64];
  __shared__ u16   xt[64][130];      // [pos][c], stride 260B -> 2-way writes
  int t = threadIdx.x;
  int lane = t & 63, cq = t >> 6;
  int b = blockIdx.x >> 6;
  int posb = (blockIdx.x & 63) << 6;
  const float* xb = x + ((size_t)b * CCH) * NTOK + posb;
  for (int i = 0; i < 32; ++i) {
    int c = cq * 32 + i;
    tile[c][lane] = xb[(size_t)c * NTOK + lane];
  }
  __syncthreads();
  float s = 0.f, s2 = 0.f;
  for (int i = 0; i < 32; ++i) {
    float v = tile[cq * 32 + i][lane];
    s += v; s2 += v * v;
  }
  red[0][cq][lane] = s; red[1][cq][lane] = s2;
  __syncthreads();
  float mu  = (red[0][0][lane] + red[0][1][lane] + red[0][2][lane] + red[0][3][lane]) * (1.f / 128.f);
  float ex2 = (red[1][0][lane] + red[1][1][lane] + red[1][2][lane] + red[1][3][lane]) * (1.f / 128.f);
  float rstd = rsqrtf(ex2 - mu * mu + 1e-5f);
  for (int i = 0; i < 32; ++i) {
    int c = cq * 32 + i;
    float v = (tile[c][lane] - mu) * rstd * gamma[c] + beta[c];
    xt[lane][c] = f2bf(v);
  }
  __syncthreads();
  // coalesced copy-out as dwords
  u32* dst = (u32*)(xn + ((size_t)(b * NTOK + posb)) * CCH);
  for (int i = 0; i < 16; ++i) {
    int idx = i * 256 + t;          // 0..4095 dwords (64 rows x 64 dwords)
    int row = idx >> 6, col2 = idx & 63;
    dst[idx] = *(const u32*)&xt[row][col2 * 2];
  }
}

// ---------------- kernel 2: QKV projection GEMM -----------------------------
// out[token][j] = sum_c W[j][c]*xn[token][c], j in 0..191
// Q,K token-major [token][32]; V channel-major Vt[b][c][token]
__global__ __launch_bounds__(256) void qkv_kernel(
    const u16* __restrict__ xn, const u16* __restrict__ wcomb,
    u16* __restrict__ Qg, u16* __restrict__ Kg, u16* __restrict__ Vt) {
  int t = threadIdx.x;
  int w = t >> 6, lane = t & 63;
  int row16 = lane & 15, kgrp = lane >> 4;
  int tok0 = blockIdx.x * 64;
  int tokA = tok0 + w * 16 + row16;
  bf16x8 af[4];
  for (int ks = 0; ks < 4; ++ks)
    af[ks] = *(const bf16x8*)&xn[(size_t)tokA * CCH + ks * 32 + kgrp * 8];
  f32x4 zero = {0.f, 0.f, 0.f, 0.f};
  f32x4 acc[12];
  for (int nt = 0; nt < 12; ++nt) {
    acc[nt] = zero;
    for (int ks = 0; ks < 4; ++ks) {
      bf16x8 bf = *(const bf16x8*)&wcomb[(size_t)(nt * 16 + row16) * CCH + ks * 32 + kgrp * 8];
      acc[nt] = mfma16(af[ks], bf, acc[nt]);
    }
  }
  int b = tok0 >> 12;
  for (int nt = 0; nt < 12; ++nt) {
    int col = nt * 16 + row16;
    for (int r = 0; r < 4; ++r) {
      int token = tok0 + w * 16 + kgrp * 4 + r;
      u16 val = f2bf(acc[nt][r]);
      if (col < 32)       Qg[(size_t)token * DQK + col] = val;
      else if (col < 64)  Kg[(size_t)token * DQK + (col - 32)] = val;
      else                Vt[((size_t)b * CCH + (col - 64)) * NTOK + (token & (NTOK - 1))] = val;
    }
  }
}

// ---------------- kernel 3: flash attention ---------------------------------
// block: 64 queries (4 waves x 16), loop 64 key-tiles of 64
__global__ __launch_bounds__(256) void attn_kernel(
    const u16* __restrict__ Qg, const u16* __restrict__ Kg,
    const u16* __restrict__ Vt, u16* __restrict__ attO) {
  __shared__ u16 Ktile[64][56];    // stride 112B (mult 16, ~2-way banks)
  __shared__ u16 Vl[128][88];      // [c][k], stride 176B
  __shared__ u16 Pl[4][16][88];    // per-wave P [q][k]
  int t = threadIdx.x;
  int w = t >> 6, lane = t & 63;
  int row16 = lane & 15, kgrp = lane >> 4;
  int b = blockIdx.x >> 6;
  int q0 = (blockIdx.x & 63) * 64;

  bf16x8 qf = *(const bf16x8*)&Qg[((size_t)(b * NTOK + q0 + w * 16 + row16)) * DQK + kgrp * 8];

  f32x4 zero = {0.f, 0.f, 0.f, 0.f};
  f32x4 o[8];
  for (int i = 0; i < 8; ++i) o[i] = zero;
  float m[4] = {-1e30f, -1e30f, -1e30f, -1e30f};
  float l[4] = {0.f, 0.f, 0.f, 0.f};

  int krow = t >> 2, kcol = (t & 3) * 8;   // K staging: 16B per thread
  int vc = t >> 1, vko = (t & 1) * 32;     // V staging: 64B per thread
  const u16* Kbase = Kg + (size_t)b * NTOK * DQK;
  const u16* Vbase = Vt + (size_t)b * CCH * NTOK;

  for (int kt = 0; kt < NTOK; kt += KT) {
    *(uint4*)&Ktile[krow][kcol] = *(const uint4*)&Kbase[(size_t)(kt + krow) * DQK + kcol];
    const u16* vsrc = Vbase + (size_t)vc * NTOK + kt + vko;
    for (int j = 0; j < 4; ++j)
      *(uint4*)&Vl[vc][vko + j * 8] = *(const uint4*)&vsrc[j * 8];
    __syncthreads();

    // S = Q K^T : 4 tiles of 16 keys
    f32x4 sacc[4];
    for (int nt = 0; nt < 4; ++nt) {
      bf16x8 kf = *(const bf16x8*)&Ktile[nt * 16 + row16][kgrp * 8];
      sacc[nt] = mfma16(qf, kf, zero);
    }
    // online softmax. lane holds rows 4*kgrp+r, key col = nt*16+row16
    float tmax[4], tsum[4], p[4][4], scale[4];
    for (int r = 0; r < 4; ++r)
      tmax[r] = fmaxf(fmaxf(sacc[0][r], sacc[1][r]), fmaxf(sacc[2][r], sacc[3][r]));
    for (int mk = 1; mk <= 8; mk <<= 1)
      for (int r = 0; r < 4; ++r)
        tmax[r] = fmaxf(tmax[r], __shfl_xor(tmax[r], mk));
    for (int r = 0; r < 4; ++r) {
      float mn = fmaxf(m[r], tmax[r]);
      scale[r] = __expf(m[r] - mn);
      m[r] = mn;
      float ssum = 0.f;
      for (int nt = 0; nt < 4; ++nt) {
        float pv = __expf(sacc[nt][r] - mn);
        p[nt][r] = pv;
        ssum += pv;
      }
      tsum[r] = ssum;
    }
    for (int mk = 1; mk <= 8; mk <<= 1)
      for (int r = 0; r < 4; ++r)
        tsum[r] += __shfl_xor(tsum[r], mk);
    for (int r = 0; r < 4; ++r) l[r] = l[r] * scale[r] + tsum[r];
    for (int nt = 0; nt < 8; ++nt)
      for (int r = 0; r < 4; ++r)
        o[nt][r] *= scale[r];
    // P -> LDS (re-fragment for PV A-operand)
    for (int nt = 0; nt < 4; ++nt)
      for (int r = 0; r < 4; ++r)
        Pl[w][kgrp * 4 + r][nt * 16 + row16] = f2bf(p[nt][r]);
    // O += P V   (K dim = 64 keys = 2 MFMA k-steps; N = 128 ch = 8 tiles)
    for (int ks = 0; ks < 2; ++ks) {
      bf16x8 pf = *(const bf16x8*)&Pl[w][row16][ks * 32 + kgrp * 8];
      for (int nt = 0; nt < 8; ++nt) {
        bf16x8 vf = *(const bf16x8*)&Vl[nt * 16 + row16][ks * 32 + kgrp * 8];
        o[nt] = mfma16(pf, vf, o[nt]);
      }
    }
    __syncthreads();
  }
  // epilogue: normalize and write token-major bf16
  int tokb = b * NTOK + q0 + w * 16;
  for (int r = 0; r < 4; ++r) {
    float inv = 1.f / l[r];
    int token = tokb + kgrp * 4 + r;
    for (int nt = 0; nt < 8; ++nt)
      attO[(size_t)token * CCH + nt * 16 + row16] = f2bf(o[nt][r] * inv);
  }
}

// ---------------- kernel 4: Wo GEMM + bias + residual -----------------------
__global__ __launch_bounds__(256) void out_kernel(
    const u16* __restrict__ attO, const u16* __restrict__ wcomb,
    const float* __restrict__ bo, const float* __restrict__ x,
    float* __restrict__ out) {
  int t = threadIdx.x;
  int w = t >> 6, lane = t & 63;
  int row16 = lane & 15, kgrp = lane >> 4;
  int tok0 = blockIdx.x * 64;
  int b = tok0 >> 12, tloc = tok0 & (NTOK - 1);
  bf16x8 af[4];
  int tokA = tok0 + w * 16 + row16;
  for (int ks = 0; ks < 4; ++ks)
    af[ks] = *(const bf16x8*)&attO[(size_t)tokA * CCH + ks * 32 + kgrp * 8];
  f32x4 zero = {0.f, 0.f, 0.f, 0.f};
  f32x4 acc[8];
  for (int nt = 0; nt < 8; ++nt) {
    acc[nt] = zero;
    for (int ks = 0; ks < 4; ++ks) {
      bf16x8 bf = *(const bf16x8*)&wcomb[(size_t)(192 + nt * 16 + row16) * CCH + ks * 32 + kgrp * 8];
      acc[nt] = mfma16(af[ks], bf, acc[nt]);
    }
  }
  for (int nt = 0; nt < 8; ++nt) {
    int cout = nt * 16 + row16;
    float bias = bo[cout];
    size_t base = ((size_t)b * CCH + cout) * NTOK + tloc + w * 16 + kgrp * 4;
    float4 xr = *(const float4*)&x[base];
    float4 ov;
    ov.x = acc[nt][0] + bias + xr.x;
    ov.y = acc[nt][1] + bias + xr.y;
    ov.z = acc[nt][2] + bias + xr.z;
    ov.w = acc[nt][3] + bias + xr.w;
    *(float4*)&out[base] = ov;
  }
}

extern "C" void kernel_launch(void* const* d_in, const int* in_sizes, int n_in,
                              void* d_out, int out_size, void* d_ws, size_t ws_size,
                              hipStream_t stream) {
  const float* x     = (const float*)d_in[0];
  const float* gamma = (const float*)d_in[1];
  const float* beta  = (const float*)d_in[2];
  const float* Wq    = (const float*)d_in[3];
  const float* Wk    = (const float*)d_in[4];
  const float* Wv    = (const float*)d_in[5];
  const float* Wo    = (const float*)d_in[6];
  const float* bo    = (const float*)d_in[7];
  float* out = (float*)d_out;

  unsigned char* ws = (unsigned char*)d_ws;
  u16* xn    = (u16*)(ws);                 //  8,388,608 B  [32768][128]
  u16* Qg    = (u16*)(ws + 8388608);       //  2,097,152 B  [32768][32]
  u16* Kg    = (u16*)(ws + 10485760);      //  2,097,152 B  [32768][32]
  u16* Vt    = (u16*)(ws + 12582912);      //  8,388,608 B  [8][128][4096]
  u16* attO  = (u16*)(ws + 20971520);      //  8,388,608 B  [32768][128]
  u16* wcomb = (u16*)(ws + 29360128);      //     81,920 B  [320][128]

  wconv_kernel<<<160, 256, 0, stream>>>(Wq, Wk, Wv, Wo, wcomb);
  ln_kernel<<<512, 256, 0, stream>>>(x, gamma, beta, xn);
  qkv_kernel<<<512, 256, 0, stream>>>(xn, wcomb, Qg, Kg, Vt);
  attn_kernel<<<512, 256, 0, stream>>>(Qg, Kg, Vt, attO);
  out_kernel<<<512, 256, 0, stream>>>(attO, wcomb, bo, x, out);
}

// Round 2
// 141.020 us; speedup vs baseline: 1.6905x; 1.6905x over previous
//
#include <hip/hip_runtime.h>

// Problem: B=8, C=128, H=W=64 -> N=4096 tokens/batch, 32768 total. d_qk=32.
// LN(channel) -> Q/K/V 1x1 conv -> full spatial attention -> Wo + bias + residual.
// R2: split-K(2) attention + max-free softmax (exp2, Q pre-scaled by log2e).

#define NB 8
#define CCH 128
#define NTOK 4096      // tokens per batch (H*W)
#define DQK 32
#define KT 64          // key tile
#define KHALF 2048     // keys per split-K half

typedef __attribute__((ext_vector_type(8))) short bf16x8;  // 8 bf16 = 4 VGPR
typedef __attribute__((ext_vector_type(4))) float f32x4;
typedef unsigned short u16;
typedef unsigned int u32;

static __device__ __forceinline__ f32x4 mfma16(bf16x8 a, bf16x8 b, f32x4 c) {
  return __builtin_amdgcn_mfma_f32_16x16x32_bf16(a, b, c, 0, 0, 0);
}

static __device__ __forceinline__ u16 f2bf(float f) {
  union { float f; u32 u; } cv; cv.f = f;
  u32 u = cv.u;
  u += 0x7fffu + ((u >> 16) & 1u);   // round-to-nearest-even
  return (u16)(u >> 16);
}
static __device__ __forceinline__ float bf2f(u16 v) {
  union { u32 u; float f; } cv; cv.u = ((u32)v) << 16;
  return cv.f;
}

// ---------------- kernel 0: convert weights to bf16, combined [320][128] ----
// rows 0..31 Wq, 32..63 Wk, 64..191 Wv, 192..319 Wo
__global__ __launch_bounds__(256) void wconv_kernel(
    const float* __restrict__ Wq, const float* __restrict__ Wk,
    const float* __restrict__ Wv, const float* __restrict__ Wo,
    u16* __restrict__ wcomb) {
  int idx = blockIdx.x * 256 + threadIdx.x;   // 0..40959
  int r = idx >> 7;
  float v;
  if (r < 32)        v = Wq[idx];
  else if (r < 64)   v = Wk[idx - 4096];
  else if (r < 192)  v = Wv[idx - 8192];
  else               v = Wo[idx - 24576];
  wcomb[idx] = f2bf(v);
}

// ---------------- kernel 1: LayerNorm over C, write token-major bf16 --------
__global__ __launch_bounds__(256) void ln_kernel(
    const float* __restrict__ x, const float* __restrict__ gamma,
    const float* __restrict__ beta, u16* __restrict__ xn) {
  __shared__ float tile[128][64];    // [c][pos] 32 KB
  __shared__ float red[2][4][64];
  __shared__ u16   xt[64][130];      // [pos][c], stride 260B -> 2-way writes
  int t = threadIdx.x;
  int lane = t & 63, cq = t >> 6;
  int b = blockIdx.x >> 6;
  int posb = (blockIdx.x & 63) << 6;
  const float* xb = x + ((size_t)b * CCH) * NTOK + posb;
  for (int i = 0; i < 32; ++i) {
    int c = cq * 32 + i;
    tile[c][lane] = xb[(size_t)c * NTOK + lane];
  }
  __syncthreads();
  float s = 0.f, s2 = 0.f;
  for (int i = 0; i < 32; ++i) {
    float v = tile[cq * 32 + i][lane];
    s += v; s2 += v * v;
  }
  red[0][cq][lane] = s; red[1][cq][lane] = s2;
  __syncthreads();
  float mu  = (red[0][0][lane] + red[0][1][lane] + red[0][2][lane] + red[0][3][lane]) * (1.f / 128.f);
  float ex2 = (red[1][0][lane] + red[1][1][lane] + red[1][2][lane] + red[1][3][lane]) * (1.f / 128.f);
  float rstd = rsqrtf(ex2 - mu * mu + 1e-5f);
  for (int i = 0; i < 32; ++i) {
    int c = cq * 32 + i;
    float v = (tile[c][lane] - mu) * rstd * gamma[c] + beta[c];
    xt[lane][c] = f2bf(v);
  }
  __syncthreads();
  // coalesced copy-out as dwords
  u32* dst = (u32*)(xn + ((size_t)(b * NTOK + posb)) * CCH);
  for (int i = 0; i < 16; ++i) {
    int idx = i * 256 + t;          // 0..4095 dwords (64 rows x 64 dwords)
    int row = idx >> 6, col2 = idx & 63;
    dst[idx] = *(const u32*)&xt[row][col2 * 2];
  }
}

// ---------------- kernel 2: QKV projection GEMM -----------------------------
// out[token][j] = sum_c W[j][c]*xn[token][c], j in 0..191
// Q (scaled by log2e) token-major [token][32]; K token-major; V channel-major Vt[b][c][token]
__global__ __launch_bounds__(256) void qkv_kernel(
    const u16* __restrict__ xn, const u16* __restrict__ wcomb,
    u16* __restrict__ Qg, u16* __restrict__ Kg, u16* __restrict__ Vt) {
  int t = threadIdx.x;
  int w = t >> 6, lane = t & 63;
  int row16 = lane & 15, kgrp = lane >> 4;
  int tok0 = blockIdx.x * 64;
  int tokA = tok0 + w * 16 + row16;
  bf16x8 af[4];
  for (int ks = 0; ks < 4; ++ks)
    af[ks] = *(const bf16x8*)&xn[(size_t)tokA * CCH + ks * 32 + kgrp * 8];
  f32x4 zero = {0.f, 0.f, 0.f, 0.f};
  f32x4 acc[12];
  for (int nt = 0; nt < 12; ++nt) {
    acc[nt] = zero;
    for (int ks = 0; ks < 4; ++ks) {
      bf16x8 bf = *(const bf16x8*)&wcomb[(size_t)(nt * 16 + row16) * CCH + ks * 32 + kgrp * 8];
      acc[nt] = mfma16(af[ks], bf, acc[nt]);
    }
  }
  int b = tok0 >> 12;
  for (int nt = 0; nt < 12; ++nt) {
    int col = nt * 16 + row16;
    for (int r = 0; r < 4; ++r) {
      int token = tok0 + w * 16 + kgrp * 4 + r;
      if (col < 32) {
        Qg[(size_t)token * DQK + col] = f2bf(acc[nt][r] * 1.44269504f); // log2e folded
      } else if (col < 64) {
        Kg[(size_t)token * DQK + (col - 32)] = f2bf(acc[nt][r]);
      } else {
        Vt[((size_t)b * CCH + (col - 64)) * NTOK + (token & (NTOK - 1))] = f2bf(acc[nt][r]);
      }
    }
  }
}

// ---------------- kernel 3: flash attention, split-K over key halves --------
// block: 64 queries (4 waves x 16) x 2048 keys. Max-free softmax:
// p = exp2(s_log2) (Q pre-scaled), partial unnormalized O + partial l out.
__global__ __launch_bounds__(256) void attn_kernel(
    const u16* __restrict__ Qg, const u16* __restrict__ Kg,
    const u16* __restrict__ Vt, u16* __restrict__ Op0, u16* __restrict__ Op1,
    float* __restrict__ lp) {
  __shared__ u16 Ktile[64][56];    // stride 112B (granule step 7 -> 2-way)
  __shared__ u16 Vl[128][88];      // [c][k], stride 176B (granule step 11 -> 2-way)
  __shared__ u16 Pl[4][16][72];    // per-wave P [q][k], stride 144B (step 9)
  int t = threadIdx.x;
  int w = t >> 6, lane = t & 63;
  int row16 = lane & 15, kgrp = lane >> 4;
  int half = blockIdx.x & 1;
  int q0 = ((blockIdx.x >> 1) & 63) * 64;
  int b = blockIdx.x >> 7;
  int kt0 = half * KHALF;

  bf16x8 qf = *(const bf16x8*)&Qg[((size_t)(b * NTOK + q0 + w * 16 + row16)) * DQK + kgrp * 8];

  f32x4 zero = {0.f, 0.f, 0.f, 0.f};
  f32x4 o[8];
  for (int i = 0; i < 8; ++i) o[i] = zero;
  float l[4] = {0.f, 0.f, 0.f, 0.f};

  int krow = t >> 2, kcol = (t & 3) * 8;   // K staging: 16B per thread
  int vc = t >> 1, vko = (t & 1) * 32;     // V staging: 64B per thread
  const u16* Kbase = Kg + (size_t)b * NTOK * DQK;
  const u16* Vbase = Vt + (size_t)b * CCH * NTOK;

  for (int kt = kt0; kt < kt0 + KHALF; kt += KT) {
    *(uint4*)&Ktile[krow][kcol] = *(const uint4*)&Kbase[(size_t)(kt + krow) * DQK + kcol];
    const u16* vsrc = Vbase + (size_t)vc * NTOK + kt + vko;
    for (int j = 0; j < 4; ++j)
      *(uint4*)&Vl[vc][vko + j * 8] = *(const uint4*)&vsrc[j * 8];
    __syncthreads();

    // S = Q K^T : 4 tiles of 16 keys. lane: rows q=kgrp*4+r, col key=nt*16+row16
    f32x4 sacc[4];
    for (int nt = 0; nt < 4; ++nt) {
      bf16x8 kf = *(const bf16x8*)&Ktile[nt * 16 + row16][kgrp * 8];
      sacc[nt] = mfma16(qf, kf, zero);
    }
    // max-free softmax: p = exp2(s), lane-local l partials
    float p[4][4];
    for (int nt = 0; nt < 4; ++nt)
      for (int r = 0; r < 4; ++r) {
        float pv = __builtin_amdgcn_exp2f(fminf(sacc[nt][r], 110.f));
        p[nt][r] = pv;
        l[r] += pv;
      }
    // P -> LDS (re-fragment for PV A-operand)
    for (int nt = 0; nt < 4; ++nt)
      for (int r = 0; r < 4; ++r)
        Pl[w][kgrp * 4 + r][nt * 16 + row16] = f2bf(p[nt][r]);
    // O += P V   (K dim = 64 keys = 2 MFMA k-steps; N = 128 ch = 8 tiles)
    for (int ks = 0; ks < 2; ++ks) {
      bf16x8 pf = *(const bf16x8*)&Pl[w][row16][ks * 32 + kgrp * 8];
      for (int nt = 0; nt < 8; ++nt) {
        bf16x8 vf = *(const bf16x8*)&Vl[nt * 16 + row16][ks * 32 + kgrp * 8];
        o[nt] = mfma16(pf, vf, o[nt]);
      }
    }
    __syncthreads();
  }
  // epilogue: reduce l across the 16 key-lanes (keys nt*16+row16 -> sum over row16)
  for (int mk = 1; mk <= 8; mk <<= 1)
    for (int r = 0; r < 4; ++r)
      l[r] += __shfl_xor(l[r], mk);
  // write unnormalized partial O (bf16) + partial l
  u16* Opw = half ? Op1 : Op0;
  size_t obase = ((size_t)(b * NTOK + q0 + w * 16)) * CCH;
  for (int r = 0; r < 4; ++r) {
    int trow = kgrp * 4 + r;
    for (int nt = 0; nt < 8; ++nt)
      Opw[obase + (size_t)trow * CCH + nt * 16 + row16] = f2bf(o[nt][r]);
  }
  if (row16 == 0) {
    for (int r = 0; r < 4; ++r)
      lp[half * 32768 + b * NTOK + q0 + w * 16 + kgrp * 4 + r] = l[r];
  }
}

// ---------------- kernel 4: combine halves + Wo GEMM + bias + residual ------
__global__ __launch_bounds__(256) void out_kernel(
    const u16* __restrict__ Op0, const u16* __restrict__ Op1,
    const float* __restrict__ lp, const u16* __restrict__ wcomb,
    const float* __restrict__ bo, const float* __restrict__ x,
    float* __restrict__ out) {
  int t = threadIdx.x;
  int w = t >> 6, lane = t & 63;
  int row16 = lane & 15, kgrp = lane >> 4;
  int tok0 = blockIdx.x * 64;
  int b = tok0 >> 12, tloc = tok0 & (NTOK - 1);
  int tokA = tok0 + w * 16 + row16;
  float inv = 1.f / (lp[tokA] + lp[32768 + tokA]);
  bf16x8 af[4];
  for (int ks = 0; ks < 4; ++ks) {
    bf16x8 a0 = *(const bf16x8*)&Op0[(size_t)tokA * CCH + ks * 32 + kgrp * 8];
    bf16x8 a1 = *(const bf16x8*)&Op1[(size_t)tokA * CCH + ks * 32 + kgrp * 8];
    bf16x8 av;
    for (int j = 0; j < 8; ++j) {
      float f = (bf2f((u16)a0[j]) + bf2f((u16)a1[j])) * inv;
      av[j] = (short)f2bf(f);
    }
    af[ks] = av;
  }
  f32x4 zero = {0.f, 0.f, 0.f, 0.f};
  f32x4 acc[8];
  for (int nt = 0; nt < 8; ++nt) {
    acc[nt] = zero;
    for (int ks = 0; ks < 4; ++ks) {
      bf16x8 bf = *(const bf16x8*)&wcomb[(size_t)(192 + nt * 16 + row16) * CCH + ks * 32 + kgrp * 8];
      acc[nt] = mfma16(af[ks], bf, acc[nt]);
    }
  }
  for (int nt = 0; nt < 8; ++nt) {
    int cout = nt * 16 + row16;
    float bias = bo[cout];
    size_t base = ((size_t)b * CCH + cout) * NTOK + tloc + w * 16 + kgrp * 4;
    float4 xr = *(const float4*)&x[base];
    float4 ov;
    ov.x = acc[nt][0] + bias + xr.x;
    ov.y = acc[nt][1] + bias + xr.y;
    ov.z = acc[nt][2] + bias + xr.z;
    ov.w = acc[nt][3] + bias + xr.w;
    *(float4*)&out[base] = ov;
  }
}

extern "C" void kernel_launch(void* const* d_in, const int* in_sizes, int n_in,
                              void* d_out, int out_size, void* d_ws, size_t ws_size,
                              hipStream_t stream) {
  const float* x     = (const float*)d_in[0];
  const float* gamma = (const float*)d_in[1];
  const float* beta  = (const float*)d_in[2];
  const float* Wq    = (const float*)d_in[3];
  const float* Wk    = (const float*)d_in[4];
  const float* Wv    = (const float*)d_in[5];
  const float* Wo    = (const float*)d_in[6];
  const float* bo    = (const float*)d_in[7];
  float* out = (float*)d_out;

  unsigned char* ws = (unsigned char*)d_ws;
  u16* xn    = (u16*)(ws);                 //  8,388,608 B  [32768][128]  (reused as Op0)
  u16* Qg    = (u16*)(ws + 8388608);       //  2,097,152 B  [32768][32]
  u16* Kg    = (u16*)(ws + 10485760);      //  2,097,152 B  [32768][32]
  u16* Vt    = (u16*)(ws + 12582912);      //  8,388,608 B  [8][128][4096]
  u16* Op1   = (u16*)(ws + 20971520);      //  8,388,608 B  [32768][128]
  float* lp  = (float*)(ws + 29360128);    //    262,144 B  [2][32768]
  u16* wcomb = (u16*)(ws + 29622272);      //     81,920 B  [320][128]
  u16* Op0   = xn;                         // xn dead after qkv_kernel

  wconv_kernel<<<160, 256, 0, stream>>>(Wq, Wk, Wv, Wo, wcomb);
  ln_kernel<<<512, 256, 0, stream>>>(x, gamma, beta, xn);
  qkv_kernel<<<512, 256, 0, stream>>>(xn, wcomb, Qg, Kg, Vt);
  attn_kernel<<<1024, 256, 0, stream>>>(Qg, Kg, Vt, Op0, Op1, lp);
  out_kernel<<<512, 256, 0, stream>>>(Op0, Op1, lp, wcomb, bo, x, out);
}

// Round 3
// 101.289 us; speedup vs baseline: 2.3536x; 1.3923x over previous
//
#include <hip/hip_runtime.h>

// B=8, C=128, H=W=64 -> N=4096 tokens/batch. d_qk=32.
// R3: swapped QK^T + key-permuted V (P stays in-lane), 32q/wave,
// XOR-swizzled LDS via pre-swizzled global_load_lds, 2-phase dbuf.

#define NB 8
#define CCH 128
#define NTOK 4096
#define DQK 32
#define KT 64
#define KHALF 2048

typedef __attribute__((ext_vector_type(8))) short bf16x8;
typedef __attribute__((ext_vector_type(4))) float f32x4;
typedef unsigned short u16;
typedef unsigned int u32;

static __device__ __forceinline__ f32x4 mfma16(bf16x8 a, bf16x8 b, f32x4 c) {
  return __builtin_amdgcn_mfma_f32_16x16x32_bf16(a, b, c, 0, 0, 0);
}
static __device__ __forceinline__ u16 f2bf(float f) {
  union { float f; u32 u; } cv; cv.f = f;
  u32 u = cv.u;
  u += 0x7fffu + ((u >> 16) & 1u);
  return (u16)(u >> 16);
}
static __device__ __forceinline__ float bf2f(u16 v) {
  union { u32 u; float f; } cv; cv.u = ((u32)v) << 16;
  return cv.f;
}
static __device__ __forceinline__ u32 cvtpk(float lo, float hi) {
  u32 d;
  asm("v_cvt_pk_bf16_f32 %0, %1, %2" : "=v"(d) : "v"(lo), "v"(hi));
  return d;
}
static __device__ __forceinline__ void gload16(const void* g, void* l) {
  __builtin_amdgcn_global_load_lds(
      (const __attribute__((address_space(1))) void*)g,
      (__attribute__((address_space(3))) void*)l, 16, 0, 0);
}

// ---------------- kernel 0: weights -> bf16 [320][128] ----------------------
__global__ __launch_bounds__(256) void wconv_kernel(
    const float* __restrict__ Wq, const float* __restrict__ Wk,
    const float* __restrict__ Wv, const float* __restrict__ Wo,
    u16* __restrict__ wcomb) {
  int idx = blockIdx.x * 256 + threadIdx.x;
  int r = idx >> 7;
  float v;
  if (r < 32)        v = Wq[idx];
  else if (r < 64)   v = Wk[idx - 4096];
  else if (r < 192)  v = Wv[idx - 8192];
  else               v = Wo[idx - 24576];
  wcomb[idx] = f2bf(v);
}

// ---------------- kernel 1: LayerNorm over C -> token-major bf16 ------------
__global__ __launch_bounds__(256) void ln_kernel(
    const float* __restrict__ x, const float* __restrict__ gamma,
    const float* __restrict__ beta, u16* __restrict__ xn) {
  __shared__ float tile[128][64];
  __shared__ float red[2][4][64];
  __shared__ u16   xt[64][130];
  int t = threadIdx.x;
  int lane = t & 63, cq = t >> 6;
  int b = blockIdx.x >> 6;
  int posb = (blockIdx.x & 63) << 6;
  const float* xb = x + ((size_t)b * CCH) * NTOK + posb;
  for (int i = 0; i < 32; ++i) {
    int c = cq * 32 + i;
    tile[c][lane] = xb[(size_t)c * NTOK + lane];
  }
  __syncthreads();
  float s = 0.f, s2 = 0.f;
  for (int i = 0; i < 32; ++i) {
    float v = tile[cq * 32 + i][lane];
    s += v; s2 += v * v;
  }
  red[0][cq][lane] = s; red[1][cq][lane] = s2;
  __syncthreads();
  float mu  = (red[0][0][lane] + red[0][1][lane] + red[0][2][lane] + red[0][3][lane]) * (1.f / 128.f);
  float ex2 = (red[1][0][lane] + red[1][1][lane] + red[1][2][lane] + red[1][3][lane]) * (1.f / 128.f);
  float rstd = rsqrtf(ex2 - mu * mu + 1e-5f);
  for (int i = 0; i < 32; ++i) {
    int c = cq * 32 + i;
    float v = (tile[c][lane] - mu) * rstd * gamma[c] + beta[c];
    xt[lane][c] = f2bf(v);
  }
  __syncthreads();
  u32* dst = (u32*)(xn + ((size_t)(b * NTOK + posb)) * CCH);
  for (int i = 0; i < 16; ++i) {
    int idx = i * 256 + t;
    int row = idx >> 6, col2 = idx & 63;
    dst[idx] = *(const u32*)&xt[row][col2 * 2];
  }
}

// ---------------- kernel 2: QKV projection GEMM -----------------------------
// Q (pre-scaled by log2e) [token][32]; K [token][32]; V channel-major with
// key order permuted within each 32-token group: k' matches S^T residency.
__global__ __launch_bounds__(256) void qkv_kernel(
    const u16* __restrict__ xn, const u16* __restrict__ wcomb,
    u16* __restrict__ Qg, u16* __restrict__ Kg, u16* __restrict__ Vt) {
  int t = threadIdx.x;
  int w = t >> 6, lane = t & 63;
  int row16 = lane & 15, kgrp = lane >> 4;
  int tok0 = blockIdx.x * 64;
  int tokA = tok0 + w * 16 + row16;
  bf16x8 af[4];
  for (int ks = 0; ks < 4; ++ks)
    af[ks] = *(const bf16x8*)&xn[(size_t)tokA * CCH + ks * 32 + kgrp * 8];
  f32x4 zero = {0.f, 0.f, 0.f, 0.f};
  f32x4 acc[12];
  for (int nt = 0; nt < 12; ++nt) {
    acc[nt] = zero;
    for (int ks = 0; ks < 4; ++ks) {
      bf16x8 bf = *(const bf16x8*)&wcomb[(size_t)(nt * 16 + row16) * CCH + ks * 32 + kgrp * 8];
      acc[nt] = mfma16(af[ks], bf, acc[nt]);
    }
  }
  int b = tok0 >> 12;
  for (int nt = 0; nt < 12; ++nt) {
    int col = nt * 16 + row16;
    for (int r = 0; r < 4; ++r) {
      int token = tok0 + w * 16 + kgrp * 4 + r;
      if (col < 32) {
        Qg[(size_t)token * DQK + col] = f2bf(acc[nt][r] * 1.44269504f);
      } else if (col < 64) {
        Kg[(size_t)token * DQK + (col - 32)] = f2bf(acc[nt][r]);
      } else {
        int tl = token & (NTOK - 1);
        int kp = (tl & ~31) | ((tl & 12) << 1) | ((tl & 16) >> 2) | (tl & 3);
        Vt[((size_t)b * CCH + (col - 64)) * NTOK + kp] = f2bf(acc[nt][r]);
      }
    }
  }
}

// ---------------- kernel 3: flash attention ---------------------------------
// 4 waves x 32q = 128 q/block; split-K(2); 64-key tiles, double-buffered.
// K LDS: key-pair rows (128B), 16B slot: phys=(k>>1)*8 + (((k&1)*4+f)^((k>>1)&7))
// V LDS: [c][8 slots], phys = c*8 + (s ^ (c&7)); V global pre-permuted.
__global__ __launch_bounds__(256) void attn_kernel(
    const u16* __restrict__ Qg, const u16* __restrict__ Kg,
    const u16* __restrict__ Vt, u16* __restrict__ Op0, u16* __restrict__ Op1,
    float* __restrict__ lp) {
  __shared__ u16 lds[2][10240];   // per buf: K 2048 u16 (4KB) + V 8192 u16 (16KB)
  int t = threadIdx.x;
  int w = t >> 6, lane = t & 63;
  int row16 = lane & 15, kgrp = lane >> 4;

  int logical = ((blockIdx.x & 7) << 6) | (blockIdx.x >> 3);  // XCD-chunked
  int qblk = logical & 31;
  int half = (logical >> 5) & 1;
  int b = logical >> 6;
  int q0 = qblk * 128;
  int kt0 = half * KHALF;

  // Q fragments (B-operand of swapped QK^T): 2 q-subtiles of 16
  const u16* Qb = Qg + ((size_t)(b * NTOK + q0 + w * 32)) * DQK;
  bf16x8 qf0 = *(const bf16x8*)&Qb[(size_t)row16 * DQK + kgrp * 8];
  bf16x8 qf1 = *(const bf16x8*)&Qb[(size_t)(16 + row16) * DQK + kgrp * 8];

  // per-thread staging sources (inverse-XOR-swizzled globals)
  int pr = t >> 3, e8 = t & 7;
  int korig = e8 ^ (pr & 7);
  int kkey = pr * 2 + (korig >> 2);
  int kfs = korig & 3;
  const u16* ksrc = Kg + (size_t)(b * NTOK + kt0 + kkey) * DQK + kfs * 8;
  int cV = t >> 3;
  int sV = e8 ^ (cV & 7);
  const u16* vsrc = Vt + ((size_t)b * CCH + cV) * NTOK + kt0 + sV * 8;

  int kdst = w * 512;           // u16 idx within K region (per-wave base)
  int vdst = w * 512;           // within each V issue region (2048 u16)

  f32x4 zero = {0.f, 0.f, 0.f, 0.f};
  f32x4 o0[8], o1[8];
#pragma unroll
  for (int i = 0; i < 8; ++i) { o0[i] = zero; o1[i] = zero; }
  float l0 = 0.f, l1 = 0.f;

  auto stage = [&](int bi, int tile) {
    const u16* kp_ = ksrc + (size_t)tile * (KT * DQK);
    gload16(kp_, &lds[bi][kdst]);
    const u16* vp_ = vsrc + tile * KT;
    gload16(vp_,          &lds[bi][2048 + vdst]);
    gload16(vp_ + 131072, &lds[bi][2048 + 2048 + vdst]);
    gload16(vp_ + 262144, &lds[bi][2048 + 4096 + vdst]);
    gload16(vp_ + 393216, &lds[bi][2048 + 6144 + vdst]);
  };

  auto compute = [&](int bi) {
    const u16* kb = &lds[bi][0];
    const u16* vb = &lds[bi][2048];
    // swapped QK^T: sacc[qs][nt], lane holds S[key=nt*16+4*kgrp+r][q=qs*16+row16]
    f32x4 sa0[4], sa1[4];
#pragma unroll
    for (int nt = 0; nt < 4; ++nt) {
      int slot = (nt * 8 + (row16 >> 1)) * 8 +
                 ((((row16 & 1) << 2) + kgrp) ^ (row16 >> 1));
      bf16x8 kf = *(const bf16x8*)&kb[slot * 8];
      sa0[nt] = mfma16(kf, qf0, zero);
      sa1[nt] = mfma16(kf, qf1, zero);
    }
    // p = exp2(s) in place; lane-local l partials
#pragma unroll
    for (int nt = 0; nt < 4; ++nt)
      for (int r = 0; r < 4; ++r) {
        float p0 = __builtin_amdgcn_exp2f(sa0[nt][r]);
        float p1 = __builtin_amdgcn_exp2f(sa1[nt][r]);
        sa0[nt][r] = p0; sa1[nt][r] = p1;
        l0 += p0; l1 += p1;
      }
    // pack P fragments fully in-lane (key-permuted V makes this the A-frag)
    union PU { u32 d[4]; bf16x8 v; };
    PU pf0[2], pf1[2];
#pragma unroll
    for (int ks = 0; ks < 2; ++ks) {
      pf0[ks].d[0] = cvtpk(sa0[2 * ks][0], sa0[2 * ks][1]);
      pf0[ks].d[1] = cvtpk(sa0[2 * ks][2], sa0[2 * ks][3]);
      pf0[ks].d[2] = cvtpk(sa0[2 * ks + 1][0], sa0[2 * ks + 1][1]);
      pf0[ks].d[3] = cvtpk(sa0[2 * ks + 1][2], sa0[2 * ks + 1][3]);
      pf1[ks].d[0] = cvtpk(sa1[2 * ks][0], sa1[2 * ks][1]);
      pf1[ks].d[1] = cvtpk(sa1[2 * ks][2], sa1[2 * ks][3]);
      pf1[ks].d[2] = cvtpk(sa1[2 * ks + 1][0], sa1[2 * ks + 1][1]);
      pf1[ks].d[3] = cvtpk(sa1[2 * ks + 1][2], sa1[2 * ks + 1][3]);
    }
    // O += P V
#pragma unroll
    for (int ks = 0; ks < 2; ++ks)
#pragma unroll
      for (int ntc = 0; ntc < 8; ++ntc) {
        int vslot = (ntc * 16 + row16) * 8 + (((ks << 2) + kgrp) ^ (row16 & 7));
        bf16x8 vf = *(const bf16x8*)&vb[vslot * 8];
        o0[ntc] = mfma16(pf0[ks].v, vf, o0[ntc]);
        o1[ntc] = mfma16(pf1[ks].v, vf, o1[ntc]);
      }
  };

  stage(0, 0);
  asm volatile("s_waitcnt vmcnt(0)" ::: "memory");
  __builtin_amdgcn_s_barrier();
  int cur = 0;
  for (int tile = 0; tile < 31; ++tile) {
    stage(cur ^ 1, tile + 1);
    compute(cur);
    asm volatile("s_waitcnt vmcnt(0)" ::: "memory");
    __builtin_amdgcn_s_barrier();
    cur ^= 1;
  }
  compute(cur);

  // epilogue: l replicated across kgrp groups; write unnormalized partial O
  for (int mk = 16; mk <= 32; mk <<= 1) {
    l0 += __shfl_xor(l0, mk);
    l1 += __shfl_xor(l1, mk);
  }
  u16* Opw = half ? Op1 : Op0;
  int tokb = b * NTOK + q0 + w * 32;
#pragma unroll
  for (int r = 0; r < 4; ++r) {
    int tk0 = tokb + kgrp * 4 + r;
    int tk1 = tokb + 16 + kgrp * 4 + r;
#pragma unroll
    for (int ntc = 0; ntc < 8; ++ntc) {
      Opw[(size_t)tk0 * CCH + ntc * 16 + row16] = f2bf(o0[ntc][r]);
      Opw[(size_t)tk1 * CCH + ntc * 16 + row16] = f2bf(o1[ntc][r]);
    }
  }
  if (kgrp == 0) {
    lp[half * 32768 + tokb + row16] = l0;
    lp[half * 32768 + tokb + 16 + row16] = l1;
  }
}

// ---------------- kernel 4: combine halves + Wo GEMM + bias + residual ------
__global__ __launch_bounds__(256) void out_kernel(
    const u16* __restrict__ Op0, const u16* __restrict__ Op1,
    const float* __restrict__ lp, const u16* __restrict__ wcomb,
    const float* __restrict__ bo, const float* __restrict__ x,
    float* __restrict__ out) {
  int t = threadIdx.x;
  int w = t >> 6, lane = t & 63;
  int row16 = lane & 15, kgrp = lane >> 4;
  int tok0 = blockIdx.x * 64;
  int b = tok0 >> 12, tloc = tok0 & (NTOK - 1);
  int tokA = tok0 + w * 16 + row16;
  float inv = 1.f / (lp[tokA] + lp[32768 + tokA]);
  bf16x8 af[4];
  for (int ks = 0; ks < 4; ++ks) {
    bf16x8 a0 = *(const bf16x8*)&Op0[(size_t)tokA * CCH + ks * 32 + kgrp * 8];
    bf16x8 a1 = *(const bf16x8*)&Op1[(size_t)tokA * CCH + ks * 32 + kgrp * 8];
    bf16x8 av;
    for (int j = 0; j < 8; ++j) {
      float f = (bf2f((u16)a0[j]) + bf2f((u16)a1[j])) * inv;
      av[j] = (short)f2bf(f);
    }
    af[ks] = av;
  }
  f32x4 zero = {0.f, 0.f, 0.f, 0.f};
  f32x4 acc[8];
  for (int nt = 0; nt < 8; ++nt) {
    acc[nt] = zero;
    for (int ks = 0; ks < 4; ++ks) {
      bf16x8 bf = *(const bf16x8*)&wcomb[(size_t)(192 + nt * 16 + row16) * CCH + ks * 32 + kgrp * 8];
      acc[nt] = mfma16(af[ks], bf, acc[nt]);
    }
  }
  for (int nt = 0; nt < 8; ++nt) {
    int cout = nt * 16 + row16;
    float bias = bo[cout];
    size_t base = ((size_t)b * CCH + cout) * NTOK + tloc + w * 16 + kgrp * 4;
    float4 xr = *(const float4*)&x[base];
    float4 ov;
    ov.x = acc[nt][0] + bias + xr.x;
    ov.y = acc[nt][1] + bias + xr.y;
    ov.z = acc[nt][2] + bias + xr.z;
    ov.w = acc[nt][3] + bias + xr.w;
    *(float4*)&out[base] = ov;
  }
}

extern "C" void kernel_launch(void* const* d_in, const int* in_sizes, int n_in,
                              void* d_out, int out_size, void* d_ws, size_t ws_size,
                              hipStream_t stream) {
  const float* x     = (const float*)d_in[0];
  const float* gamma = (const float*)d_in[1];
  const float* beta  = (const float*)d_in[2];
  const float* Wq    = (const float*)d_in[3];
  const float* Wk    = (const float*)d_in[4];
  const float* Wv    = (const float*)d_in[5];
  const float* Wo    = (const float*)d_in[6];
  const float* bo    = (const float*)d_in[7];
  float* out = (float*)d_out;

  unsigned char* ws = (unsigned char*)d_ws;
  u16* xn    = (u16*)(ws);                 //  8 MB [32768][128] (reused as Op0)
  u16* Qg    = (u16*)(ws + 8388608);       //  2 MB
  u16* Kg    = (u16*)(ws + 10485760);      //  2 MB
  u16* Vt    = (u16*)(ws + 12582912);      //  8 MB [8][128][4096] key-permuted
  u16* Op1   = (u16*)(ws + 20971520);      //  8 MB
  float* lp  = (float*)(ws + 29360128);    //  256 KB [2][32768]
  u16* wcomb = (u16*)(ws + 29622272);      //  80 KB
  u16* Op0   = xn;

  wconv_kernel<<<160, 256, 0, stream>>>(Wq, Wk, Wv, Wo, wcomb);
  ln_kernel<<<512, 256, 0, stream>>>(x, gamma, beta, xn);
  qkv_kernel<<<512, 256, 0, stream>>>(xn, wcomb, Qg, Kg, Vt);
  attn_kernel<<<512, 256, 0, stream>>>(Qg, Kg, Vt, Op0, Op1, lp);
  out_kernel<<<512, 256, 0, stream>>>(Op0, Op1, lp, wcomb, bo, x, out);
}

// Round 4
// 93.800 us; speedup vs baseline: 2.5415x; 1.0798x over previous
//
#include <hip/hip_runtime.h>

// B=8, C=128, H=W=64 -> N=4096 tokens/batch. d_qk=32.
// R4: 64q attention blocks (grid 1024, 4 blocks/CU), fused LN+QKV.
// Swapped QK^T + key-permuted V (P in-lane), XOR-swizzled LDS via
// pre-swizzled global_load_lds, 2-phase dbuf.

#define NB 8
#define CCH 128
#define NTOK 4096
#define DQK 32
#define KT 64
#define KHALF 2048

typedef __attribute__((ext_vector_type(8))) short bf16x8;
typedef __attribute__((ext_vector_type(4))) float f32x4;
typedef unsigned short u16;
typedef unsigned int u32;

static __device__ __forceinline__ f32x4 mfma16(bf16x8 a, bf16x8 b, f32x4 c) {
  return __builtin_amdgcn_mfma_f32_16x16x32_bf16(a, b, c, 0, 0, 0);
}
static __device__ __forceinline__ u16 f2bf(float f) {
  union { float f; u32 u; } cv; cv.f = f;
  u32 u = cv.u;
  u += 0x7fffu + ((u >> 16) & 1u);
  return (u16)(u >> 16);
}
static __device__ __forceinline__ float bf2f(u16 v) {
  union { u32 u; float f; } cv; cv.u = ((u32)v) << 16;
  return cv.f;
}
static __device__ __forceinline__ u32 cvtpk(float lo, float hi) {
  u32 d;
  asm("v_cvt_pk_bf16_f32 %0, %1, %2" : "=v"(d) : "v"(lo), "v"(hi));
  return d;
}
static __device__ __forceinline__ void gload16(const void* g, void* l) {
  __builtin_amdgcn_global_load_lds(
      (const __attribute__((address_space(1))) void*)g,
      (__attribute__((address_space(3))) void*)l, 16, 0, 0);
}

// ---------------- kernel 0: weights -> bf16 [320][128] ----------------------
__global__ __launch_bounds__(256) void wconv_kernel(
    const float* __restrict__ Wq, const float* __restrict__ Wk,
    const float* __restrict__ Wv, const float* __restrict__ Wo,
    u16* __restrict__ wcomb) {
  int idx = blockIdx.x * 256 + threadIdx.x;
  int r = idx >> 7;
  float v;
  if (r < 32)        v = Wq[idx];
  else if (r < 64)   v = Wk[idx - 4096];
  else if (r < 192)  v = Wv[idx - 8192];
  else               v = Wo[idx - 24576];
  wcomb[idx] = f2bf(v);
}

// ---------------- kernel 1: fused LayerNorm + QKV projection ----------------
// 64 tokens/block. LN stats in LDS, normalized xt stays in LDS, MFMA reads
// A-frags directly. Q pre-scaled by log2e; V written key-permuted channel-major.
__global__ __launch_bounds__(256) void lnqkv_kernel(
    const float* __restrict__ x, const float* __restrict__ gamma,
    const float* __restrict__ beta, const u16* __restrict__ wcomb,
    u16* __restrict__ Qg, u16* __restrict__ Kg, u16* __restrict__ Vt) {
  __shared__ float tile[128][64];
  __shared__ float red[2][4][64];
  __shared__ u16   xt[64][130];
  int t = threadIdx.x;
  int lane = t & 63, cq = t >> 6;
  int b = blockIdx.x >> 6;
  int posb = (blockIdx.x & 63) << 6;
  const float* xb = x + ((size_t)b * CCH) * NTOK + posb;
  for (int i = 0; i < 32; ++i) {
    int c = cq * 32 + i;
    tile[c][lane] = xb[(size_t)c * NTOK + lane];
  }
  __syncthreads();
  float s = 0.f, s2 = 0.f;
  for (int i = 0; i < 32; ++i) {
    float v = tile[cq * 32 + i][lane];
    s += v; s2 += v * v;
  }
  red[0][cq][lane] = s; red[1][cq][lane] = s2;
  __syncthreads();
  float mu  = (red[0][0][lane] + red[0][1][lane] + red[0][2][lane] + red[0][3][lane]) * (1.f / 128.f);
  float ex2 = (red[1][0][lane] + red[1][1][lane] + red[1][2][lane] + red[1][3][lane]) * (1.f / 128.f);
  float rstd = rsqrtf(ex2 - mu * mu + 1e-5f);
  for (int i = 0; i < 32; ++i) {
    int c = cq * 32 + i;
    float v = (tile[c][lane] - mu) * rstd * gamma[c] + beta[c];
    xt[lane][c] = f2bf(v);
  }
  __syncthreads();
  // ---- QKV GEMM from LDS ----
  int w = t >> 6, row16 = lane & 15, kgrp = lane >> 4;
  bf16x8 af[4];
  for (int ks = 0; ks < 4; ++ks)
    af[ks] = *(const bf16x8*)&xt[w * 16 + row16][ks * 32 + kgrp * 8];
  f32x4 zero = {0.f, 0.f, 0.f, 0.f};
  f32x4 acc[12];
  for (int nt = 0; nt < 12; ++nt) {
    acc[nt] = zero;
    for (int ks = 0; ks < 4; ++ks) {
      bf16x8 bf = *(const bf16x8*)&wcomb[(size_t)(nt * 16 + row16) * CCH + ks * 32 + kgrp * 8];
      acc[nt] = mfma16(af[ks], bf, acc[nt]);
    }
  }
  int tok0 = b * NTOK + posb;
  for (int nt = 0; nt < 12; ++nt) {
    int col = nt * 16 + row16;
    for (int r = 0; r < 4; ++r) {
      int token = tok0 + w * 16 + kgrp * 4 + r;
      if (col < 32) {
        Qg[(size_t)token * DQK + col] = f2bf(acc[nt][r] * 1.44269504f);
      } else if (col < 64) {
        Kg[(size_t)token * DQK + (col - 32)] = f2bf(acc[nt][r]);
      } else {
        int tl = token & (NTOK - 1);
        int kp = (tl & ~31) | ((tl & 12) << 1) | ((tl & 16) >> 2) | (tl & 3);
        Vt[((size_t)b * CCH + (col - 64)) * NTOK + kp] = f2bf(acc[nt][r]);
      }
    }
  }
}

// ---------------- kernel 2: flash attention ---------------------------------
// 4 waves x 16q = 64 q/block; split-K(2); grid 1024 = 4 blocks/CU.
// K LDS: key-pair rows (128B), slot phys=(k>>1)*8 + (((k&1)*4+f)^((k>>1)&7))
// V LDS: [c][8 slots], phys = c*8 + (s ^ (c&7)); V global pre-permuted.
__global__ __launch_bounds__(256, 4) void attn_kernel(
    const u16* __restrict__ Qg, const u16* __restrict__ Kg,
    const u16* __restrict__ Vt, u16* __restrict__ Op0, u16* __restrict__ Op1,
    float* __restrict__ lp) {
  __shared__ u16 lds[2][10240];   // per buf: K 2048 u16 (4KB) + V 8192 u16 (16KB)
  int t = threadIdx.x;
  int w = t >> 6, lane = t & 63;
  int row16 = lane & 15, kgrp = lane >> 4;

  int logical = ((blockIdx.x & 7) << 7) | (blockIdx.x >> 3);  // XCD-chunked
  int qblk = logical & 63;
  int half = (logical >> 6) & 1;
  int b = logical >> 7;
  int q0 = qblk * 64;
  int kt0 = half * KHALF;

  // Q fragment (B-operand of swapped QK^T)
  bf16x8 qf = *(const bf16x8*)&Qg[((size_t)(b * NTOK + q0 + w * 16 + row16)) * DQK + kgrp * 8];

  // per-thread staging sources (inverse-XOR-swizzled globals)
  int pr = t >> 3, e8 = t & 7;
  int korig = e8 ^ (pr & 7);
  int kkey = pr * 2 + (korig >> 2);
  int kfs = korig & 3;
  const u16* ksrc = Kg + (size_t)(b * NTOK + kt0 + kkey) * DQK + kfs * 8;
  int cV = t >> 3;
  int sV = e8 ^ (cV & 7);
  const u16* vsrc = Vt + ((size_t)b * CCH + cV) * NTOK + kt0 + sV * 8;

  int kdst = w * 512;
  int vdst = w * 512;

  f32x4 zero = {0.f, 0.f, 0.f, 0.f};
  f32x4 o[8];
#pragma unroll
  for (int i = 0; i < 8; ++i) o[i] = zero;
  float l0 = 0.f;

  auto stage = [&](int bi, int tile) {
    const u16* kp_ = ksrc + (size_t)tile * (KT * DQK);
    gload16(kp_, &lds[bi][kdst]);
    const u16* vp_ = vsrc + tile * KT;
    gload16(vp_,          &lds[bi][2048 + vdst]);
    gload16(vp_ + 131072, &lds[bi][2048 + 2048 + vdst]);
    gload16(vp_ + 262144, &lds[bi][2048 + 4096 + vdst]);
    gload16(vp_ + 393216, &lds[bi][2048 + 6144 + vdst]);
  };

  auto compute = [&](int bi) {
    const u16* kb = &lds[bi][0];
    const u16* vb = &lds[bi][2048];
    f32x4 sa[4];
#pragma unroll
    for (int nt = 0; nt < 4; ++nt) {
      int slot = (nt * 8 + (row16 >> 1)) * 8 +
                 ((((row16 & 1) << 2) + kgrp) ^ (row16 >> 1));
      bf16x8 kf = *(const bf16x8*)&kb[slot * 8];
      sa[nt] = mfma16(kf, qf, zero);
    }
#pragma unroll
    for (int nt = 0; nt < 4; ++nt)
      for (int r = 0; r < 4; ++r) {
        float p0 = __builtin_amdgcn_exp2f(sa[nt][r]);
        sa[nt][r] = p0;
        l0 += p0;
      }
    union PU { u32 d[4]; bf16x8 v; };
    PU pf[2];
#pragma unroll
    for (int ks = 0; ks < 2; ++ks) {
      pf[ks].d[0] = cvtpk(sa[2 * ks][0], sa[2 * ks][1]);
      pf[ks].d[1] = cvtpk(sa[2 * ks][2], sa[2 * ks][3]);
      pf[ks].d[2] = cvtpk(sa[2 * ks + 1][0], sa[2 * ks + 1][1]);
      pf[ks].d[3] = cvtpk(sa[2 * ks + 1][2], sa[2 * ks + 1][3]);
    }
#pragma unroll
    for (int ks = 0; ks < 2; ++ks)
#pragma unroll
      for (int ntc = 0; ntc < 8; ++ntc) {
        int vslot = (ntc * 16 + row16) * 8 + (((ks << 2) + kgrp) ^ (row16 & 7));
        bf16x8 vf = *(const bf16x8*)&vb[vslot * 8];
        o[ntc] = mfma16(pf[ks].v, vf, o[ntc]);
      }
  };

  stage(0, 0);
  asm volatile("s_waitcnt vmcnt(0)" ::: "memory");
  __builtin_amdgcn_s_barrier();
  int cur = 0;
  for (int tile = 0; tile < 31; ++tile) {
    stage(cur ^ 1, tile + 1);
    compute(cur);
    asm volatile("s_waitcnt vmcnt(0)" ::: "memory");
    __builtin_amdgcn_s_barrier();
    cur ^= 1;
  }
  compute(cur);

  // epilogue: l replicated across kgrp groups; write unnormalized partial O
  for (int mk = 16; mk <= 32; mk <<= 1)
    l0 += __shfl_xor(l0, mk);
  u16* Opw = half ? Op1 : Op0;
  int tokb = b * NTOK + q0 + w * 16;
#pragma unroll
  for (int r = 0; r < 4; ++r) {
    int tk = tokb + kgrp * 4 + r;
#pragma unroll
    for (int ntc = 0; ntc < 8; ++ntc)
      Opw[(size_t)tk * CCH + ntc * 16 + row16] = f2bf(o[ntc][r]);
  }
  if (kgrp == 0)
    lp[half * 32768 + tokb + row16] = l0;
}

// ---------------- kernel 3: combine halves + Wo GEMM + bias + residual ------
__global__ __launch_bounds__(256) void out_kernel(
    const u16* __restrict__ Op0, const u16* __restrict__ Op1,
    const float* __restrict__ lp, const u16* __restrict__ wcomb,
    const float* __restrict__ bo, const float* __restrict__ x,
    float* __restrict__ out) {
  int t = threadIdx.x;
  int w = t >> 6, lane = t & 63;
  int row16 = lane & 15, kgrp = lane >> 4;
  int tok0 = blockIdx.x * 64;
  int b = tok0 >> 12, tloc = tok0 & (NTOK - 1);
  int tokA = tok0 + w * 16 + row16;
  float inv = 1.f / (lp[tokA] + lp[32768 + tokA]);
  bf16x8 af[4];
  for (int ks = 0; ks < 4; ++ks) {
    bf16x8 a0 = *(const bf16x8*)&Op0[(size_t)tokA * CCH + ks * 32 + kgrp * 8];
    bf16x8 a1 = *(const bf16x8*)&Op1[(size_t)tokA * CCH + ks * 32 + kgrp * 8];
    bf16x8 av;
    for (int j = 0; j < 8; ++j) {
      float f = (bf2f((u16)a0[j]) + bf2f((u16)a1[j])) * inv;
      av[j] = (short)f2bf(f);
    }
    af[ks] = av;
  }
  f32x4 zero = {0.f, 0.f, 0.f, 0.f};
  f32x4 acc[8];
  for (int nt = 0; nt < 8; ++nt) {
    acc[nt] = zero;
    for (int ks = 0; ks < 4; ++ks) {
      bf16x8 bf = *(const bf16x8*)&wcomb[(size_t)(192 + nt * 16 + row16) * CCH + ks * 32 + kgrp * 8];
      acc[nt] = mfma16(af[ks], bf, acc[nt]);
    }
  }
  for (int nt = 0; nt < 8; ++nt) {
    int cout = nt * 16 + row16;
    float bias = bo[cout];
    size_t base = ((size_t)b * CCH + cout) * NTOK + tloc + w * 16 + kgrp * 4;
    float4 xr = *(const float4*)&x[base];
    float4 ov;
    ov.x = acc[nt][0] + bias + xr.x;
    ov.y = acc[nt][1] + bias + xr.y;
    ov.z = acc[nt][2] + bias + xr.z;
    ov.w = acc[nt][3] + bias + xr.w;
    *(float4*)&out[base] = ov;
  }
}

extern "C" void kernel_launch(void* const* d_in, const int* in_sizes, int n_in,
                              void* d_out, int out_size, void* d_ws, size_t ws_size,
                              hipStream_t stream) {
  const float* x     = (const float*)d_in[0];
  const float* gamma = (const float*)d_in[1];
  const float* beta  = (const float*)d_in[2];
  const float* Wq    = (const float*)d_in[3];
  const float* Wk    = (const float*)d_in[4];
  const float* Wv    = (const float*)d_in[5];
  const float* Wo    = (const float*)d_in[6];
  const float* bo    = (const float*)d_in[7];
  float* out = (float*)d_out;

  unsigned char* ws = (unsigned char*)d_ws;
  u16* Op0   = (u16*)(ws);                 //  8 MB [32768][128]
  u16* Qg    = (u16*)(ws + 8388608);       //  2 MB
  u16* Kg    = (u16*)(ws + 10485760);      //  2 MB
  u16* Vt    = (u16*)(ws + 12582912);      //  8 MB [8][128][4096] key-permuted
  u16* Op1   = (u16*)(ws + 20971520);      //  8 MB
  float* lp  = (float*)(ws + 29360128);    //  256 KB [2][32768]
  u16* wcomb = (u16*)(ws + 29622272);      //  80 KB

  wconv_kernel<<<160, 256, 0, stream>>>(Wq, Wk, Wv, Wo, wcomb);
  lnqkv_kernel<<<512, 256, 0, stream>>>(x, gamma, beta, wcomb, Qg, Kg, Vt);
  attn_kernel<<<1024, 256, 0, stream>>>(Qg, Kg, Vt, Op0, Op1, lp);
  out_kernel<<<512, 256, 0, stream>>>(Op0, Op1, lp, wcomb, bo, x, out);
}

// Round 6
// 93.165 us; speedup vs baseline: 2.5589x; 1.0068x over previous
//
#include <hip/hip_runtime.h>

// B=8, C=128, H=W=64 -> N=4096 tokens/batch. d_qk=32.
// R5 (resubmit after infra failure): 32q/wave (2 q-subtiles), split-K(4) gated
// on ws_size (fallback split-2), l accumulated via ones-column MFMA.
// Swapped QK^T + key-permuted V (P in-lane), XOR-swizzled LDS via
// pre-swizzled global_load_lds, 2-phase dbuf. Fused LN+QKV.

#define NB 8
#define CCH 128
#define NTOK 4096
#define DQK 32
#define KT 64

typedef __attribute__((ext_vector_type(8))) short bf16x8;
typedef __attribute__((ext_vector_type(4))) float f32x4;
typedef unsigned short u16;
typedef unsigned int u32;

static __device__ __forceinline__ f32x4 mfma16(bf16x8 a, bf16x8 b, f32x4 c) {
  return __builtin_amdgcn_mfma_f32_16x16x32_bf16(a, b, c, 0, 0, 0);
}
static __device__ __forceinline__ u16 f2bf(float f) {
  union { float f; u32 u; } cv; cv.f = f;
  u32 u = cv.u;
  u += 0x7fffu + ((u >> 16) & 1u);
  return (u16)(u >> 16);
}
static __device__ __forceinline__ float bf2f(u16 v) {
  union { u32 u; float f; } cv; cv.u = ((u32)v) << 16;
  return cv.f;
}
static __device__ __forceinline__ u32 cvtpk(float lo, float hi) {
  u32 d;
  asm("v_cvt_pk_bf16_f32 %0, %1, %2" : "=v"(d) : "v"(lo), "v"(hi));
  return d;
}
static __device__ __forceinline__ void gload16(const void* g, void* l) {
  __builtin_amdgcn_global_load_lds(
      (const __attribute__((address_space(1))) void*)g,
      (__attribute__((address_space(3))) void*)l, 16, 0, 0);
}

// ---------------- kernel 0: weights -> bf16 [320][128] ----------------------
__global__ __launch_bounds__(256) void wconv_kernel(
    const float* __restrict__ Wq, const float* __restrict__ Wk,
    const float* __restrict__ Wv, const float* __restrict__ Wo,
    u16* __restrict__ wcomb) {
  int idx = blockIdx.x * 256 + threadIdx.x;
  int r = idx >> 7;
  float v;
  if (r < 32)        v = Wq[idx];
  else if (r < 64)   v = Wk[idx - 4096];
  else if (r < 192)  v = Wv[idx - 8192];
  else               v = Wo[idx - 24576];
  wcomb[idx] = f2bf(v);
}

// ---------------- kernel 1: fused LayerNorm + QKV projection ----------------
__global__ __launch_bounds__(256) void lnqkv_kernel(
    const float* __restrict__ x, const float* __restrict__ gamma,
    const float* __restrict__ beta, const u16* __restrict__ wcomb,
    u16* __restrict__ Qg, u16* __restrict__ Kg, u16* __restrict__ Vt) {
  __shared__ float tile[128][64];
  __shared__ float red[2][4][64];
  __shared__ u16   xt[64][130];
  int t = threadIdx.x;
  int lane = t & 63, cq = t >> 6;
  int b = blockIdx.x >> 6;
  int posb = (blockIdx.x & 63) << 6;
  const float* xb = x + ((size_t)b * CCH) * NTOK + posb;
  for (int i = 0; i < 32; ++i) {
    int c = cq * 32 + i;
    tile[c][lane] = xb[(size_t)c * NTOK + lane];
  }
  __syncthreads();
  float s = 0.f, s2 = 0.f;
  for (int i = 0; i < 32; ++i) {
    float v = tile[cq * 32 + i][lane];
    s += v; s2 += v * v;
  }
  red[0][cq][lane] = s; red[1][cq][lane] = s2;
  __syncthreads();
  float mu  = (red[0][0][lane] + red[0][1][lane] + red[0][2][lane] + red[0][3][lane]) * (1.f / 128.f);
  float ex2 = (red[1][0][lane] + red[1][1][lane] + red[1][2][lane] + red[1][3][lane]) * (1.f / 128.f);
  float rstd = rsqrtf(ex2 - mu * mu + 1e-5f);
  for (int i = 0; i < 32; ++i) {
    int c = cq * 32 + i;
    float v = (tile[c][lane] - mu) * rstd * gamma[c] + beta[c];
    xt[lane][c] = f2bf(v);
  }
  __syncthreads();
  int w = t >> 6, row16 = lane & 15, kgrp = lane >> 4;
  bf16x8 af[4];
  for (int ks = 0; ks < 4; ++ks)
    af[ks] = *(const bf16x8*)&xt[w * 16 + row16][ks * 32 + kgrp * 8];
  f32x4 zero = {0.f, 0.f, 0.f, 0.f};
  f32x4 acc[12];
  for (int nt = 0; nt < 12; ++nt) {
    acc[nt] = zero;
    for (int ks = 0; ks < 4; ++ks) {
      bf16x8 bf = *(const bf16x8*)&wcomb[(size_t)(nt * 16 + row16) * CCH + ks * 32 + kgrp * 8];
      acc[nt] = mfma16(af[ks], bf, acc[nt]);
    }
  }
  int tok0 = b * NTOK + posb;
  for (int nt = 0; nt < 12; ++nt) {
    int col = nt * 16 + row16;
    for (int r = 0; r < 4; ++r) {
      int token = tok0 + w * 16 + kgrp * 4 + r;
      if (col < 32) {
        Qg[(size_t)token * DQK + col] = f2bf(acc[nt][r] * 1.44269504f);
      } else if (col < 64) {
        Kg[(size_t)token * DQK + (col - 32)] = f2bf(acc[nt][r]);
      } else {
        int tl = token & (NTOK - 1);
        int kp = (tl & ~31) | ((tl & 12) << 1) | ((tl & 16) >> 2) | (tl & 3);
        Vt[((size_t)b * CCH + (col - 64)) * NTOK + kp] = f2bf(acc[nt][r]);
      }
    }
  }
}

// ---------------- kernel 2: flash attention ---------------------------------
// 4 waves x 32q = 128 q/block; split-K(NS); grid 256*NS.
// K LDS: key-pair rows (128B), slot phys=(k>>1)*8 + (((k&1)*4+f)^((k>>1)&7))
// V LDS: [c][8 slots of 16B], phys = c*64u16 + (s^(c&7))*8; V pre-permuted.
// l via ones-column MFMA: ol = P * [1,0,...,0]^T accumulated in f32.
template <int NS>
__global__ __launch_bounds__(256, 4) void attn_kernel(
    const u16* __restrict__ Qg, const u16* __restrict__ Kg,
    const u16* __restrict__ Vt, u16* __restrict__ Op,
    float* __restrict__ lp) {
  __shared__ u16 lds[2][10240];   // per buf: K 2048 u16 (4KB) + V 8192 u16 (16KB)
  constexpr int KSEG = NTOK / NS;         // keys per split segment
  constexpr int NTILE = KSEG / KT;        // tiles per block
  constexpr int BSH = (NS == 4) ? 7 : 6;  // qblk(5) + part bits
  int t = threadIdx.x;
  int w = t >> 6, lane = t & 63;
  int row16 = lane & 15, kgrp = lane >> 4;

  int cpx = (256 * NS) >> 3;
  int logical = (blockIdx.x & 7) * cpx + (blockIdx.x >> 3);  // XCD-chunked
  int qblk = logical & 31;
  int part = (logical >> 5) & (NS - 1);
  int b = logical >> BSH;
  int q0 = qblk * 128;
  int kt0 = part * KSEG;

  // Q fragments (B-operand of swapped QK^T): 2 q-subtiles of 16
  const u16* Qb = Qg + ((size_t)(b * NTOK + q0 + w * 32)) * DQK;
  bf16x8 qf0 = *(const bf16x8*)&Qb[(size_t)row16 * DQK + kgrp * 8];
  bf16x8 qf1 = *(const bf16x8*)&Qb[(size_t)(16 + row16) * DQK + kgrp * 8];

  // ones B-fragment: B[k][col] = (col==0) ? 1 : 0  (col = row16)
  bf16x8 ones_b;
  {
    short one = (short)0x3F80;
    short val = (row16 == 0) ? one : (short)0;
    for (int j = 0; j < 8; ++j) ones_b[j] = val;
  }

  // per-thread staging sources (inverse-XOR-swizzled globals)
  int pr = t >> 3, e8 = t & 7;
  int korig = e8 ^ (pr & 7);
  int kkey = pr * 2 + (korig >> 2);
  int kfs = korig & 3;
  const u16* ksrc = Kg + (size_t)(b * NTOK + kt0 + kkey) * DQK + kfs * 8;
  int cV = t >> 3;
  int sV = e8 ^ (cV & 7);
  const u16* vsrc = Vt + ((size_t)b * CCH + cV) * NTOK + kt0 + sV * 8;

  int kdst = w * 512;
  int vdst = w * 512;

  f32x4 zero = {0.f, 0.f, 0.f, 0.f};
  f32x4 o0[8], o1[8], ol0, ol1;
#pragma unroll
  for (int i = 0; i < 8; ++i) { o0[i] = zero; o1[i] = zero; }
  ol0 = zero; ol1 = zero;

  auto stage = [&](int bi, int tile) {
    const u16* kp_ = ksrc + (size_t)tile * (KT * DQK);
    gload16(kp_, &lds[bi][kdst]);
    const u16* vp_ = vsrc + tile * KT;
    gload16(vp_,          &lds[bi][2048 + vdst]);
    gload16(vp_ + 131072, &lds[bi][2048 + 2048 + vdst]);
    gload16(vp_ + 262144, &lds[bi][2048 + 4096 + vdst]);
    gload16(vp_ + 393216, &lds[bi][2048 + 6144 + vdst]);
  };

  auto compute = [&](int bi) {
    const u16* kb = &lds[bi][0];
    const u16* vb = &lds[bi][2048];
    f32x4 sa0[4], sa1[4];
#pragma unroll
    for (int nt = 0; nt < 4; ++nt) {
      int slot = (nt * 8 + (row16 >> 1)) * 8 +
                 ((((row16 & 1) << 2) + kgrp) ^ (row16 >> 1));
      bf16x8 kf = *(const bf16x8*)&kb[slot * 8];
      sa0[nt] = mfma16(kf, qf0, zero);
      sa1[nt] = mfma16(kf, qf1, zero);
    }
#pragma unroll
    for (int nt = 0; nt < 4; ++nt)
      for (int r = 0; r < 4; ++r) {
        sa0[nt][r] = __builtin_amdgcn_exp2f(sa0[nt][r]);
        sa1[nt][r] = __builtin_amdgcn_exp2f(sa1[nt][r]);
      }
    union PU { u32 d[4]; bf16x8 v; };
    PU pf0[2], pf1[2];
#pragma unroll
    for (int ks = 0; ks < 2; ++ks) {
      pf0[ks].d[0] = cvtpk(sa0[2 * ks][0], sa0[2 * ks][1]);
      pf0[ks].d[1] = cvtpk(sa0[2 * ks][2], sa0[2 * ks][3]);
      pf0[ks].d[2] = cvtpk(sa0[2 * ks + 1][0], sa0[2 * ks + 1][1]);
      pf0[ks].d[3] = cvtpk(sa0[2 * ks + 1][2], sa0[2 * ks + 1][3]);
      pf1[ks].d[0] = cvtpk(sa1[2 * ks][0], sa1[2 * ks][1]);
      pf1[ks].d[1] = cvtpk(sa1[2 * ks][2], sa1[2 * ks][3]);
      pf1[ks].d[2] = cvtpk(sa1[2 * ks + 1][0], sa1[2 * ks + 1][1]);
      pf1[ks].d[3] = cvtpk(sa1[2 * ks + 1][2], sa1[2 * ks + 1][3]);
    }
    // l accumulation on the MFMA pipe
    ol0 = mfma16(pf0[0].v, ones_b, ol0);
    ol0 = mfma16(pf0[1].v, ones_b, ol0);
    ol1 = mfma16(pf1[0].v, ones_b, ol1);
    ol1 = mfma16(pf1[1].v, ones_b, ol1);
#pragma unroll
    for (int ks = 0; ks < 2; ++ks)
#pragma unroll
      for (int ntc = 0; ntc < 8; ++ntc) {
        int vslot = (ntc * 16 + row16) * 8 + (((ks << 2) + kgrp) ^ (row16 & 7));
        bf16x8 vf = *(const bf16x8*)&vb[vslot * 8];
        o0[ntc] = mfma16(pf0[ks].v, vf, o0[ntc]);
        o1[ntc] = mfma16(pf1[ks].v, vf, o1[ntc]);
      }
  };

  stage(0, 0);
  asm volatile("s_waitcnt vmcnt(0)" ::: "memory");
  __builtin_amdgcn_s_barrier();
  int cur = 0;
  for (int tile = 0; tile < NTILE - 1; ++tile) {
    stage(cur ^ 1, tile + 1);
    compute(cur);
    asm volatile("s_waitcnt vmcnt(0)" ::: "memory");
    __builtin_amdgcn_s_barrier();
    cur ^= 1;
  }
  compute(cur);

  // epilogue: write unnormalized partial O + l (from ones-MFMA, col0 lanes)
  u16* Opw = Op + (size_t)part * (32768 * CCH);
  int tokb = b * NTOK + q0 + w * 32;
#pragma unroll
  for (int r = 0; r < 4; ++r) {
    int tk0 = tokb + kgrp * 4 + r;
    int tk1 = tokb + 16 + kgrp * 4 + r;
#pragma unroll
    for (int ntc = 0; ntc < 8; ++ntc) {
      Opw[(size_t)tk0 * CCH + ntc * 16 + row16] = f2bf(o0[ntc][r]);
      Opw[(size_t)tk1 * CCH + ntc * 16 + row16] = f2bf(o1[ntc][r]);
    }
  }
  if (row16 == 0) {
#pragma unroll
    for (int r = 0; r < 4; ++r) {
      lp[part * 32768 + tokb + kgrp * 4 + r] = ol0[r];
      lp[part * 32768 + tokb + 16 + kgrp * 4 + r] = ol1[r];
    }
  }
}

// ---------------- kernel 3: combine parts + Wo GEMM + bias + residual -------
__global__ __launch_bounds__(256) void out_kernel(
    const u16* __restrict__ Op, const float* __restrict__ lp, int ns,
    const u16* __restrict__ wcomb, const float* __restrict__ bo,
    const float* __restrict__ x, float* __restrict__ out) {
  int t = threadIdx.x;
  int w = t >> 6, lane = t & 63;
  int row16 = lane & 15, kgrp = lane >> 4;
  int tok0 = blockIdx.x * 64;
  int b = tok0 >> 12, tloc = tok0 & (NTOK - 1);
  int tokA = tok0 + w * 16 + row16;
  float lsum = 0.f;
  for (int j = 0; j < ns; ++j) lsum += lp[j * 32768 + tokA];
  float inv = 1.f / lsum;
  bf16x8 af[4];
  for (int ks = 0; ks < 4; ++ks) {
    float sum[8] = {0.f, 0.f, 0.f, 0.f, 0.f, 0.f, 0.f, 0.f};
    for (int j = 0; j < ns; ++j) {
      bf16x8 a = *(const bf16x8*)&Op[(size_t)j * (32768 * CCH) +
                                     (size_t)tokA * CCH + ks * 32 + kgrp * 8];
      for (int e = 0; e < 8; ++e) sum[e] += bf2f((u16)a[e]);
    }
    bf16x8 av;
    for (int e = 0; e < 8; ++e) av[e] = (short)f2bf(sum[e] * inv);
    af[ks] = av;
  }
  f32x4 zero = {0.f, 0.f, 0.f, 0.f};
  f32x4 acc[8];
  for (int nt = 0; nt < 8; ++nt) {
    acc[nt] = zero;
    for (int ks = 0; ks < 4; ++ks) {
      bf16x8 bf = *(const bf16x8*)&wcomb[(size_t)(192 + nt * 16 + row16) * CCH + ks * 32 + kgrp * 8];
      acc[nt] = mfma16(af[ks], bf, acc[nt]);
    }
  }
  for (int nt = 0; nt < 8; ++nt) {
    int cout = nt * 16 + row16;
    float bias = bo[cout];
    size_t base = ((size_t)b * CCH + cout) * NTOK + tloc + w * 16 + kgrp * 4;
    float4 xr = *(const float4*)&x[base];
    float4 ov;
    ov.x = acc[nt][0] + bias + xr.x;
    ov.y = acc[nt][1] + bias + xr.y;
    ov.z = acc[nt][2] + bias + xr.z;
    ov.w = acc[nt][3] + bias + xr.w;
    *(float4*)&out[base] = ov;
  }
}

extern "C" void kernel_launch(void* const* d_in, const int* in_sizes, int n_in,
                              void* d_out, int out_size, void* d_ws, size_t ws_size,
                              hipStream_t stream) {
  const float* x     = (const float*)d_in[0];
  const float* gamma = (const float*)d_in[1];
  const float* beta  = (const float*)d_in[2];
  const float* Wq    = (const float*)d_in[3];
  const float* Wk    = (const float*)d_in[4];
  const float* Wv    = (const float*)d_in[5];
  const float* Wo    = (const float*)d_in[6];
  const float* bo    = (const float*)d_in[7];
  float* out = (float*)d_out;

  unsigned char* ws = (unsigned char*)d_ws;
  u16* Qg    = (u16*)(ws);                  //  2 MB
  u16* Kg    = (u16*)(ws + 2097152);        //  2 MB
  u16* Vt    = (u16*)(ws + 4194304);        //  8 MB [8][128][4096] key-permuted
  u16* wcomb = (u16*)(ws + 12582912);       //  80 KB
  float* lp  = (float*)(ws + 12664832);     //  ns*128 KB
  u16* Op    = (u16*)(ws + 13189120);       //  ns*8 MB

  // split-4 needs 13189120 + 4*8388608 = 46743552 bytes of workspace
  int ns = (ws_size >= 46743552u) ? 4 : 2;

  wconv_kernel<<<160, 256, 0, stream>>>(Wq, Wk, Wv, Wo, wcomb);
  lnqkv_kernel<<<512, 256, 0, stream>>>(x, gamma, beta, wcomb, Qg, Kg, Vt);
  if (ns == 4)
    attn_kernel<4><<<1024, 256, 0, stream>>>(Qg, Kg, Vt, Op, lp);
  else
    attn_kernel<2><<<512, 256, 0, stream>>>(Qg, Kg, Vt, Op, lp);
  out_kernel<<<512, 256, 0, stream>>>(Op, lp, ns, wcomb, bo, x, out);
}